// Round 6
// baseline (302.945 us; speedup 1.0000x reference)
//
#include <hip/hip_runtime.h>

#define D 128
typedef unsigned short ushort_t;
typedef __attribute__((ext_vector_type(8))) short bf16x8;
typedef __attribute__((ext_vector_type(4))) float f32x4;

// ---------------- helpers ----------------
__device__ __forceinline__ float wred_max(float v){
#pragma unroll
  for (int o = 1; o < 64; o <<= 1) v = fmaxf(v, __shfl_xor(v, o, 64));
  return v;
}
__device__ __forceinline__ float wred_sum(float v){
#pragma unroll
  for (int o = 1; o < 64; o <<= 1) v += __shfl_xor(v, o, 64);
  return v;
}
__device__ __forceinline__ int wred_sum_i(int v){
#pragma unroll
  for (int o = 1; o < 64; o <<= 1) v += __shfl_xor(v, o, 64);
  return v;
}
__device__ __forceinline__ unsigned short f2bf(float f){
  unsigned u = __float_as_uint(f);
  unsigned r = (u + 0x7FFFu + ((u >> 16) & 1u)) >> 16;   // RNE
  return (unsigned short)r;
}
__device__ __forceinline__ float bflo(unsigned u){ return __uint_as_float(u << 16); }
__device__ __forceinline__ float bfhi(unsigned u){ return __uint_as_float(u & 0xFFFF0000u); }

// ---------------- init: pack 3 W's (blocks 0..191) + zero counts (rest) ----------------
// B frag for 16x16x32: lane l holds B[k][c], c = ct*16+(l&15), k = s*32+(l>>4)*8+e.
__global__ __launch_bounds__(256) void k_init(const float* __restrict__ W0,
                                              const float* __restrict__ W1,
                                              const float* __restrict__ W2,
                                              ushort_t* __restrict__ Wp,
                                              int* __restrict__ counts, int n){
  int b = blockIdx.x;
  if (b < 192){
    int wi = b >> 6;
    const float* W = wi == 0 ? W0 : (wi == 1 ? W1 : W2);
    ushort_t* dst = Wp + wi * 2 * 16384;
    int idx = (b & 63) * 256 + threadIdx.x;     // 0..16383
    int k = idx >> 7, c = idx & 127;
    float w = W[idx];
    unsigned short hi = f2bf(w);
    float r = w - __uint_as_float((unsigned)hi << 16);
    unsigned short lo = f2bf(r);
    int ct = c >> 4, s = k >> 5, lane = (c & 15) | (((k >> 3) & 3) << 4), e = k & 7;
    int off = ((ct * 4 + s) * 64 + lane) * 8 + e;
    dst[off] = hi;
    dst[16384 + off] = lo;
  } else {
    int i = (b - 192) * 256 + threadIdx.x;
    if (i < n) counts[i] = 0;
  }
}

__global__ __launch_bounds__(256) void k_hist(const int* __restrict__ dst, int E, int EP,
                                              int* __restrict__ counts){
  int e = blockIdx.x * blockDim.x + threadIdx.x;
  if (e >= EP) return;
  int d = (e < E) ? dst[e] : (e - E);   // tail = self loops
  atomicAdd(&counts[d], 1);
}

__global__ __launch_bounds__(256) void k_scan1(const int* __restrict__ counts, int n,
                                               int* __restrict__ excl, int* __restrict__ bsum){
  __shared__ int ws[4];
  int tid = threadIdx.x, lane = tid & 63, wid = tid >> 6;
  int i = blockIdx.x * 256 + tid;
  int v = (i < n) ? counts[i] : 0;
  int x = v;
#pragma unroll
  for (int o = 1; o < 64; o <<= 1){ int t = __shfl_up(x, o, 64); if (lane >= o) x += t; }
  if (lane == 63) ws[wid] = x;
  __syncthreads();
  int s0 = ws[0], s1 = ws[1], s2 = ws[2];
  int wo = (wid > 0 ? s0 : 0) + (wid > 1 ? s1 : 0) + (wid > 2 ? s2 : 0);
  if (i < n) excl[i] = wo + x - v;
  if (tid == 255) bsum[blockIdx.x] = wo + x;
}

// adds self-computed bsum prefix (replaces old scan2+scan3); inits cursor
__global__ __launch_bounds__(256) void k_scan3(int* __restrict__ rowptr, const int* __restrict__ bsum,
                                               int* __restrict__ cursor, int n, int total){
  __shared__ int ss[4];
  int tid = threadIdx.x, lane = tid & 63, wid = tid >> 6;
  int b = blockIdx.x;
  int part = 0;
  for (int i = tid; i < b; i += 256) part += bsum[i];
  part = wred_sum_i(part);
  if (lane == 0) ss[wid] = part;
  __syncthreads();
  int off_b = ss[0] + ss[1] + ss[2] + ss[3];
  int i = b * 256 + tid;
  if (i < n){
    int v = rowptr[i] + off_b;
    rowptr[i] = v;
    cursor[i] = v;
  }
  if (b == 0 && tid == 0) rowptr[n] = total;
}

// ---------------- MFMA GEMM body (device func) ----------------
template<bool XF32>
__device__ __forceinline__ void gemm_body(int bid, const void* __restrict__ Av,
                                          const ushort_t* __restrict__ Wp,
                                          const float* __restrict__ a_src,
                                          const float* __restrict__ a_dst,
                                          ushort_t* __restrict__ Hbf,
                                          float* __restrict__ as_,
                                          float* __restrict__ ad_,
                                          int n){
  int tid = threadIdx.x;
  int wid = tid >> 6, l = tid & 63;
  int kg = l >> 4, cin = l & 15;
  int r0 = bid * 64 + wid * 16;
  int row_l = r0 + cin;
  if (row_l > n - 1) row_l = n - 1;

  bf16x8 ah[4], al[4];
  if (XF32){
    const float* xp = (const float*)Av + (size_t)row_l * D + kg * 8;
#pragma unroll
    for (int s = 0; s < 4; s++){
      float4 f0 = *(const float4*)(xp + s * 32);
      float4 f1 = *(const float4*)(xp + s * 32 + 4);
      float fv[8] = {f0.x, f0.y, f0.z, f0.w, f1.x, f1.y, f1.z, f1.w};
#pragma unroll
      for (int e = 0; e < 8; e++){
        unsigned short h = f2bf(fv[e]);
        ah[s][e] = (short)h;
        float r = fv[e] - __uint_as_float((unsigned)h << 16);
        al[s][e] = (short)f2bf(r);
      }
    }
  } else {
    const ushort_t* xp = (const ushort_t*)Av + (size_t)row_l * D + kg * 8;
#pragma unroll
    for (int s = 0; s < 4; s++) ah[s] = *(const bf16x8*)(xp + s * 32);
  }

  const bf16x8* Bh = (const bf16x8*)Wp;
  const bf16x8* Bl = (const bf16x8*)(Wp + 16384);

  f32x4 acc[8];
#pragma unroll
  for (int ct = 0; ct < 8; ct++) acc[ct] = (f32x4){0.f, 0.f, 0.f, 0.f};

#pragma unroll
  for (int ct = 0; ct < 8; ct++){
#pragma unroll
    for (int s = 0; s < 4; s++){
      bf16x8 bh = Bh[(ct * 4 + s) * 64 + l];
      bf16x8 bl = Bl[(ct * 4 + s) * 64 + l];
      acc[ct] = __builtin_amdgcn_mfma_f32_16x16x32_bf16(ah[s], bh, acc[ct], 0, 0, 0);
      acc[ct] = __builtin_amdgcn_mfma_f32_16x16x32_bf16(ah[s], bl, acc[ct], 0, 0, 0);
      if (XF32)
        acc[ct] = __builtin_amdgcn_mfma_f32_16x16x32_bf16(al[s], bh, acc[ct], 0, 0, 0);
    }
  }

  float asv[8], adv[8];
#pragma unroll
  for (int ct = 0; ct < 8; ct++){
    asv[ct] = a_src[ct * 16 + cin];
    adv[ct] = a_dst[ct * 16 + cin];
  }
#pragma unroll
  for (int j = 0; j < 4; j++){
    float ps = 0.f, pd = 0.f;
#pragma unroll
    for (int ct = 0; ct < 8; ct++){ ps += acc[ct][j] * asv[ct]; pd += acc[ct][j] * adv[ct]; }
#pragma unroll
    for (int o = 1; o < 16; o <<= 1){ ps += __shfl_xor(ps, o, 64); pd += __shfl_xor(pd, o, 64); }
    int row = r0 + kg * 4 + j;
    if (row < n){
      if (cin == 0) as_[row] = ps;
      if (cin == 1) ad_[row] = pd;
#pragma unroll
      for (int ct = 0; ct < 8; ct++)
        Hbf[(size_t)row * D + ct * 16 + cin] = f2bf(acc[ct][j]);
    }
  }
}

// layer-2/3 GEMM
__global__ __launch_bounds__(256) void k_gemm_mfma_bf(const void* __restrict__ Av,
                                                      const ushort_t* __restrict__ Wp,
                                                      const float* __restrict__ a_src,
                                                      const float* __restrict__ a_dst,
                                                      ushort_t* __restrict__ Hbf,
                                                      float* __restrict__ as_,
                                                      float* __restrict__ ad_,
                                                      int n){
  gemm_body<false>(blockIdx.x, Av, Wp, a_src, a_dst, Hbf, as_, ad_, n);
}

// fused: blocks [0, gemm_grid) = layer-1 GEMM (fp32 in); rest = CSR fill (overlapped)
__global__ __launch_bounds__(256) void k_gemm1_fill(const float* __restrict__ x,
                                                    const ushort_t* __restrict__ Wp,
                                                    const float* __restrict__ a_src,
                                                    const float* __restrict__ a_dst,
                                                    ushort_t* __restrict__ Hbf,
                                                    float* __restrict__ as_,
                                                    float* __restrict__ ad_,
                                                    int n, int gemm_grid,
                                                    const int* __restrict__ src,
                                                    const int* __restrict__ dst,
                                                    int E, int EP,
                                                    int* __restrict__ cursor,
                                                    ushort_t* __restrict__ csr){
  int b = blockIdx.x;
  if (b < gemm_grid){
    gemm_body<true>(b, x, Wp, a_src, a_dst, Hbf, as_, ad_, n);
  } else {
    int e = (b - gemm_grid) * 256 + threadIdx.x;
    if (e >= EP) return;
    int s, d;
    if (e < E){ s = src[e]; d = dst[e]; } else { s = d = e - E; }
    int pos = atomicAdd(&cursor[d], 1);
    csr[pos] = (ushort_t)s;
  }
}

// ---------------- aggregation: column-split, one wave per (node, col-half) ----------------
// grid ordered: waves [0,n) do cols 0-63, waves [n,2n) do cols 64-127 (temporal L2 split)
template<bool OUTBF>
__global__ __launch_bounds__(256) void k_agg(const unsigned* __restrict__ hb,   // 64 uints/row
                                             const ushort_t* __restrict__ csr,
                                             const int* __restrict__ rowptr,
                                             const float* __restrict__ asrc,
                                             const float* __restrict__ adst,
                                             const float* __restrict__ bias,
                                             unsigned* __restrict__ outb,
                                             float* __restrict__ outf,
                                             int relu, int n){
  int wid_g = blockIdx.x * 4 + (threadIdx.x >> 6);
  int half = (wid_g >= n) ? 1 : 0;
  int node = wid_g - half * n;
  if (node >= n) return;
  int lane = threadIdx.x & 63;
  int ll = lane & 31, hw = lane >> 5;
  int beg = rowptr[node];
  int deg = rowptr[node + 1] - beg;
  float adn = adst[node];
  float2 acc = make_float2(0.f, 0.f);
  float inv;
  const unsigned* hbase = hb + half * 32 + ll;

  if (deg <= 64){
    int s = 0; float logit = -1e30f;
    if (lane < deg){
      s = csr[beg + lane];
      float xx = asrc[s] + adn;
      logit = xx >= 0.f ? xx : 0.2f * xx;
    }
    float m = wred_max(logit);
    float p = (lane < deg) ? __expf(logit - m) : 0.f;
    float denom = wred_sum(p);
    inv = 1.f / (denom + 1e-16f);
    int j = 0;
    for (; j + 4 <= deg; j += 4){
      int sA = __shfl(s, j, 64),     sB = __shfl(s, j + 1, 64);
      int sC = __shfl(s, j + 2, 64), sD = __shfl(s, j + 3, 64);
      float aA = __shfl(p, j, 64),     aB = __shfl(p, j + 1, 64);
      float aC = __shfl(p, j + 2, 64), aD = __shfl(p, j + 3, 64);
      int   r0 = hw ? sB : sA;  float w0 = hw ? aB : aA;
      int   r1 = hw ? sD : sC;  float w1 = hw ? aD : aC;
      unsigned v0 = hbase[(size_t)r0 * 64];
      unsigned v1 = hbase[(size_t)r1 * 64];
      acc.x += w0 * bflo(v0); acc.y += w0 * bfhi(v0);
      acc.x += w1 * bflo(v1); acc.y += w1 * bfhi(v1);
    }
    for (; j < deg; j += 2){
      int sA = __shfl(s, j, 64);
      int sB = (j + 1 < deg) ? __shfl(s, j + 1, 64) : sA;
      float aA = __shfl(p, j, 64);
      float aB = (j + 1 < deg) ? __shfl(p, j + 1, 64) : 0.f;
      int r0 = hw ? sB : sA;  float w0 = hw ? aB : aA;
      unsigned v0 = hbase[(size_t)r0 * 64];
      acc.x += w0 * bflo(v0); acc.y += w0 * bfhi(v0);
    }
  } else {
    float m = -1e30f;
    for (int base = 0; base < deg; base += 64){
      float l = -1e30f;
      int idx = base + lane;
      if (idx < deg){ int sx = csr[beg + idx]; float xx = asrc[sx] + adn; l = xx >= 0.f ? xx : 0.2f * xx; }
      m = fmaxf(m, wred_max(l));
    }
    float denom = 0.f;
    for (int base = 0; base < deg; base += 64){
      float p2 = 0.f;
      int idx = base + lane;
      if (idx < deg){ int sx = csr[beg + idx]; float xx = asrc[sx] + adn; float l = xx >= 0.f ? xx : 0.2f * xx; p2 = __expf(l - m); }
      denom += wred_sum(p2);
    }
    inv = 1.f / (denom + 1e-16f);
    for (int base = 0; base < deg; base += 64){
      int cnt = deg - base; if (cnt > 64) cnt = 64;
      float p2 = 0.f; int sx = 0;
      int idx = base + lane;
      if (idx < deg){ sx = csr[beg + idx]; float xx = asrc[sx] + adn; float l = xx >= 0.f ? xx : 0.2f * xx; p2 = __expf(l - m); }
      for (int j = 0; j < cnt; j += 2){
        int sA = __shfl(sx, j, 64);
        int sB = (j + 1 < cnt) ? __shfl(sx, j + 1, 64) : sA;
        float aA = __shfl(p2, j, 64);
        float aB = (j + 1 < cnt) ? __shfl(p2, j + 1, 64) : 0.f;
        int r0 = hw ? sB : sA;  float w0 = hw ? aB : aA;
        unsigned v0 = hbase[(size_t)r0 * 64];
        acc.x += w0 * bflo(v0); acc.y += w0 * bfhi(v0);
      }
    }
  }
  acc.x += __shfl_xor(acc.x, 32, 64);
  acc.y += __shfl_xor(acc.y, 32, 64);

  if (hw == 0){
    float2 b2 = *(const float2*)&bias[half * 64 + ll * 2];
    float o0 = acc.x * inv + b2.x, o1 = acc.y * inv + b2.y;
    if (relu){ o0 = fmaxf(o0, 0.f); o1 = fmaxf(o1, 0.f); }
    if (OUTBF){
      unsigned u = (unsigned)f2bf(o0) | ((unsigned)f2bf(o1) << 16);
      outb[(size_t)node * 64 + half * 32 + ll] = u;
    } else {
      *(float2*)&outf[(size_t)node * D + half * 64 + ll * 2] = make_float2(o0, o1);
    }
  }
}

// ---------------- fused pool + final linear ----------------
__device__ __forceinline__ int lbound(const int* a, int n, int key){
  int lo = 0, hi = n;
  while (lo < hi){ int mid = (lo + hi) >> 1; if (a[mid] < key) lo = mid + 1; else hi = mid; }
  return lo;
}

__global__ __launch_bounds__(128) void k_pool_final(const float* __restrict__ x,
                                                    const int* __restrict__ batch,
                                                    const float* __restrict__ Wl,
                                                    const float* __restrict__ bl,
                                                    float* __restrict__ out, int n){
  __shared__ float pl[128];
  int g = blockIdx.x;
  int c = threadIdx.x;
  int lo = lbound(batch, n, g);
  int hi = lbound(batch, n, g + 1);
  float sum = 0.f;
  for (int i = lo; i < hi; i++) sum += x[(size_t)i * D + c];
  float cnt = (float)(hi - lo);
  pl[c] = sum / fmaxf(cnt, 1.f);
  __syncthreads();
  float acc = bl[c];
#pragma unroll 4
  for (int k = 0; k < 128; k++) acc += pl[k] * Wl[(size_t)k * D + c];
  out[(size_t)g * D + c] = acc;
}

// ---------------- launch ----------------
extern "C" void kernel_launch(void* const* d_in, const int* in_sizes, int n_in,
                              void* d_out, int out_size, void* d_ws, size_t ws_size,
                              hipStream_t stream){
  const float* x     = (const float*)d_in[0];
  const int*   ei    = (const int*)d_in[1];
  const int*   batch = (const int*)d_in[3];
  const float* gW[3]  = {(const float*)d_in[4],  (const float*)d_in[8],  (const float*)d_in[12]};
  const float* gAs[3] = {(const float*)d_in[5],  (const float*)d_in[9],  (const float*)d_in[13]};
  const float* gAd[3] = {(const float*)d_in[6],  (const float*)d_in[10], (const float*)d_in[14]};
  const float* gB[3]  = {(const float*)d_in[7],  (const float*)d_in[11], (const float*)d_in[15]};
  const float* linW = (const float*)d_in[16];
  const float* linB = (const float*)d_in[17];
  float* outp = (float*)d_out;

  int N  = in_sizes[3];
  int E  = in_sizes[1] / 2;
  int EP = E + N;
  int G  = out_size / D;

  char* ws = (char*)d_ws;
  size_t off = 0;
  auto alloc = [&](size_t bytes)->void*{
    void* p = ws + off;
    off += (bytes + 255) & ~(size_t)255;
    return p;
  };
  float*    bufF   = (float*)alloc((size_t)N * D * 4);      // layer-3 agg out (fp32)
  ushort_t* bufB   = (ushort_t*)alloc((size_t)N * D * 2);   // layer-1/2 agg out (bf16)
  ushort_t* Hbf    = (ushort_t*)alloc((size_t)N * D * 2);   // h (bf16)
  float*    as_    = (float*)alloc((size_t)N * 4);
  float*    ad_    = (float*)alloc((size_t)N * 4);
  int*      counts = (int*)  alloc((size_t)N * 4);
  int*      cursor = (int*)  alloc((size_t)N * 4);
  int*      rowptr = (int*)  alloc((size_t)(N + 1) * 4);
  ushort_t* csr    = (ushort_t*)alloc((size_t)EP * 2);
  int*      bsum   = (int*)  alloc(1024 * 4);
  ushort_t* Wp     = (ushort_t*)alloc(3 * 2 * 16384 * 2);   // 3 layers, hi+lo packed
  (void)ws_size; (void)n_in;

  const int* esrc = ei;
  const int* edst = ei + E;

  int tpb = 256;
  int egrid = (EP + tpb - 1) / tpb;
  int ngrid = (N + tpb - 1) / tpb;
  int gemm_grid = (N + 63) / 64;
  int agg_grid  = (2 * N + 3) / 4;

  k_init <<<192 + ngrid, tpb, 0, stream>>>(gW[0], gW[1], gW[2], Wp, counts, N);
  k_hist <<<egrid, tpb, 0, stream>>>(edst, E, EP, counts);
  k_scan1<<<ngrid, tpb, 0, stream>>>(counts, N, rowptr, bsum);
  k_scan3<<<ngrid, tpb, 0, stream>>>(rowptr, bsum, cursor, N, EP);

  const unsigned* hbu = (const unsigned*)Hbf;
  unsigned* bufBu = (unsigned*)bufB;

  // layer 1 GEMM (fp32 in) fused with CSR fill (independent, overlapped)
  k_gemm1_fill<<<gemm_grid + egrid, tpb, 0, stream>>>(x, Wp, gAs[0], gAd[0], Hbf, as_, ad_, N,
                                                      gemm_grid, esrc, edst, E, EP, cursor, csr);
  k_agg<true>  <<<agg_grid, tpb, 0, stream>>>(hbu, csr, rowptr, as_, ad_, gB[0], bufBu, nullptr, 1, N);
  // layer 2
  k_gemm_mfma_bf<<<gemm_grid, tpb, 0, stream>>>(bufB, Wp + 2 * 16384, gAs[1], gAd[1], Hbf, as_, ad_, N);
  k_agg<true>  <<<agg_grid, tpb, 0, stream>>>(hbu, csr, rowptr, as_, ad_, gB[1], bufBu, nullptr, 1, N);
  // layer 3
  k_gemm_mfma_bf<<<gemm_grid, tpb, 0, stream>>>(bufB, Wp + 4 * 16384, gAs[2], gAd[2], Hbf, as_, ad_, N);
  k_agg<false> <<<agg_grid, tpb, 0, stream>>>(hbu, csr, rowptr, as_, ad_, gB[2], nullptr, bufF, 0, N);

  // fused pool + final linear
  k_pool_final<<<G, 128, 0, stream>>>(bufF, batch, linW, linB, outp, N);
}

// Round 7
// 245.752 us; speedup vs baseline: 1.2327x; 1.2327x over previous
//
#include <hip/hip_runtime.h>

#define D 128
typedef unsigned short ushort_t;
typedef __attribute__((ext_vector_type(8))) short bf16x8;
typedef __attribute__((ext_vector_type(4))) float f32x4;

// ---------------- helpers ----------------
__device__ __forceinline__ float wred_max(float v){
#pragma unroll
  for (int o = 1; o < 64; o <<= 1) v = fmaxf(v, __shfl_xor(v, o, 64));
  return v;
}
__device__ __forceinline__ float wred_sum(float v){
#pragma unroll
  for (int o = 1; o < 64; o <<= 1) v += __shfl_xor(v, o, 64);
  return v;
}
__device__ __forceinline__ int wred_sum_i(int v){
#pragma unroll
  for (int o = 1; o < 64; o <<= 1) v += __shfl_xor(v, o, 64);
  return v;
}
__device__ __forceinline__ unsigned short f2bf(float f){
  unsigned u = __float_as_uint(f);
  unsigned r = (u + 0x7FFFu + ((u >> 16) & 1u)) >> 16;   // RNE
  return (unsigned short)r;
}
__device__ __forceinline__ float bflo(unsigned u){ return __uint_as_float(u << 16); }
__device__ __forceinline__ float bfhi(unsigned u){ return __uint_as_float(u & 0xFFFF0000u); }

// ---------------- init: pack 3 W's (blocks 0..191) + zero counts (rest) ----------------
// B frag for 16x16x32: lane l holds B[k][c], c = ct*16+(l&15), k = s*32+(l>>4)*8+e.
__global__ __launch_bounds__(256) void k_init(const float* __restrict__ W0,
                                              const float* __restrict__ W1,
                                              const float* __restrict__ W2,
                                              ushort_t* __restrict__ Wp,
                                              int* __restrict__ counts, int n){
  int b = blockIdx.x;
  if (b < 192){
    int wi = b >> 6;
    const float* W = wi == 0 ? W0 : (wi == 1 ? W1 : W2);
    ushort_t* dst = Wp + wi * 2 * 16384;
    int idx = (b & 63) * 256 + threadIdx.x;     // 0..16383
    int k = idx >> 7, c = idx & 127;
    float w = W[idx];
    unsigned short hi = f2bf(w);
    float r = w - __uint_as_float((unsigned)hi << 16);
    unsigned short lo = f2bf(r);
    int ct = c >> 4, s = k >> 5, lane = (c & 15) | (((k >> 3) & 3) << 4), e = k & 7;
    int off = ((ct * 4 + s) * 64 + lane) * 8 + e;
    dst[off] = hi;
    dst[16384 + off] = lo;
  } else {
    int i = (b - 192) * 256 + threadIdx.x;
    if (i < n) counts[i] = 0;
  }
}

__global__ __launch_bounds__(256) void k_hist(const int* __restrict__ dst, int E, int EP,
                                              int* __restrict__ counts){
  int e = blockIdx.x * blockDim.x + threadIdx.x;
  if (e >= EP) return;
  int d = (e < E) ? dst[e] : (e - E);   // tail = self loops
  atomicAdd(&counts[d], 1);
}

__global__ __launch_bounds__(256) void k_scan1(const int* __restrict__ counts, int n,
                                               int* __restrict__ excl, int* __restrict__ bsum){
  __shared__ int ws[4];
  int tid = threadIdx.x, lane = tid & 63, wid = tid >> 6;
  int i = blockIdx.x * 256 + tid;
  int v = (i < n) ? counts[i] : 0;
  int x = v;
#pragma unroll
  for (int o = 1; o < 64; o <<= 1){ int t = __shfl_up(x, o, 64); if (lane >= o) x += t; }
  if (lane == 63) ws[wid] = x;
  __syncthreads();
  int s0 = ws[0], s1 = ws[1], s2 = ws[2];
  int wo = (wid > 0 ? s0 : 0) + (wid > 1 ? s1 : 0) + (wid > 2 ? s2 : 0);
  if (i < n) excl[i] = wo + x - v;
  if (tid == 255) bsum[blockIdx.x] = wo + x;
}

// adds self-computed bsum prefix (replaces scan2+scan3); inits cursor
__global__ __launch_bounds__(256) void k_scan3(int* __restrict__ rowptr, const int* __restrict__ bsum,
                                               int* __restrict__ cursor, int n, int total){
  __shared__ int ss[4];
  int tid = threadIdx.x, lane = tid & 63, wid = tid >> 6;
  int b = blockIdx.x;
  int part = 0;
  for (int i = tid; i < b; i += 256) part += bsum[i];
  part = wred_sum_i(part);
  if (lane == 0) ss[wid] = part;
  __syncthreads();
  int off_b = ss[0] + ss[1] + ss[2] + ss[3];
  int i = b * 256 + tid;
  if (i < n){
    int v = rowptr[i] + off_b;
    rowptr[i] = v;
    cursor[i] = v;
  }
  if (b == 0 && tid == 0) rowptr[n] = total;
}

// ---------------- MFMA GEMM body (device func) ----------------
template<bool XF32>
__device__ __forceinline__ void gemm_body(int bid, const void* __restrict__ Av,
                                          const ushort_t* __restrict__ Wp,
                                          const float* __restrict__ a_src,
                                          const float* __restrict__ a_dst,
                                          ushort_t* __restrict__ Hbf,
                                          float* __restrict__ as_,
                                          float* __restrict__ ad_,
                                          int n){
  int tid = threadIdx.x;
  int wid = tid >> 6, l = tid & 63;
  int kg = l >> 4, cin = l & 15;
  int r0 = bid * 64 + wid * 16;
  int row_l = r0 + cin;
  if (row_l > n - 1) row_l = n - 1;

  bf16x8 ah[4], al[4];
  if (XF32){
    const float* xp = (const float*)Av + (size_t)row_l * D + kg * 8;
#pragma unroll
    for (int s = 0; s < 4; s++){
      float4 f0 = *(const float4*)(xp + s * 32);
      float4 f1 = *(const float4*)(xp + s * 32 + 4);
      float fv[8] = {f0.x, f0.y, f0.z, f0.w, f1.x, f1.y, f1.z, f1.w};
#pragma unroll
      for (int e = 0; e < 8; e++){
        unsigned short h = f2bf(fv[e]);
        ah[s][e] = (short)h;
        float r = fv[e] - __uint_as_float((unsigned)h << 16);
        al[s][e] = (short)f2bf(r);
      }
    }
  } else {
    const ushort_t* xp = (const ushort_t*)Av + (size_t)row_l * D + kg * 8;
#pragma unroll
    for (int s = 0; s < 4; s++) ah[s] = *(const bf16x8*)(xp + s * 32);
  }

  const bf16x8* Bh = (const bf16x8*)Wp;
  const bf16x8* Bl = (const bf16x8*)(Wp + 16384);

  f32x4 acc[8];
#pragma unroll
  for (int ct = 0; ct < 8; ct++) acc[ct] = (f32x4){0.f, 0.f, 0.f, 0.f};

#pragma unroll
  for (int ct = 0; ct < 8; ct++){
#pragma unroll
    for (int s = 0; s < 4; s++){
      bf16x8 bh = Bh[(ct * 4 + s) * 64 + l];
      bf16x8 bl = Bl[(ct * 4 + s) * 64 + l];
      acc[ct] = __builtin_amdgcn_mfma_f32_16x16x32_bf16(ah[s], bh, acc[ct], 0, 0, 0);
      acc[ct] = __builtin_amdgcn_mfma_f32_16x16x32_bf16(ah[s], bl, acc[ct], 0, 0, 0);
      if (XF32)
        acc[ct] = __builtin_amdgcn_mfma_f32_16x16x32_bf16(al[s], bh, acc[ct], 0, 0, 0);
    }
  }

  float asv[8], adv[8];
#pragma unroll
  for (int ct = 0; ct < 8; ct++){
    asv[ct] = a_src[ct * 16 + cin];
    adv[ct] = a_dst[ct * 16 + cin];
  }
#pragma unroll
  for (int j = 0; j < 4; j++){
    float ps = 0.f, pd = 0.f;
#pragma unroll
    for (int ct = 0; ct < 8; ct++){ ps += acc[ct][j] * asv[ct]; pd += acc[ct][j] * adv[ct]; }
#pragma unroll
    for (int o = 1; o < 16; o <<= 1){ ps += __shfl_xor(ps, o, 64); pd += __shfl_xor(pd, o, 64); }
    int row = r0 + kg * 4 + j;
    if (row < n){
      if (cin == 0) as_[row] = ps;
      if (cin == 1) ad_[row] = pd;
#pragma unroll
      for (int ct = 0; ct < 8; ct++)
        Hbf[(size_t)row * D + ct * 16 + cin] = f2bf(acc[ct][j]);
    }
  }
}

// layer-2/3 GEMM
__global__ __launch_bounds__(256) void k_gemm_mfma_bf(const void* __restrict__ Av,
                                                      const ushort_t* __restrict__ Wp,
                                                      const float* __restrict__ a_src,
                                                      const float* __restrict__ a_dst,
                                                      ushort_t* __restrict__ Hbf,
                                                      float* __restrict__ as_,
                                                      float* __restrict__ ad_,
                                                      int n){
  gemm_body<false>(blockIdx.x, Av, Wp, a_src, a_dst, Hbf, as_, ad_, n);
}

// fused: blocks [0, gemm_grid) = layer-1 GEMM (fp32 in); rest = CSR fill (overlapped)
__global__ __launch_bounds__(256) void k_gemm1_fill(const float* __restrict__ x,
                                                    const ushort_t* __restrict__ Wp,
                                                    const float* __restrict__ a_src,
                                                    const float* __restrict__ a_dst,
                                                    ushort_t* __restrict__ Hbf,
                                                    float* __restrict__ as_,
                                                    float* __restrict__ ad_,
                                                    int n, int gemm_grid,
                                                    const int* __restrict__ src,
                                                    const int* __restrict__ dst,
                                                    int E, int EP,
                                                    int* __restrict__ cursor,
                                                    ushort_t* __restrict__ csr){
  int b = blockIdx.x;
  if (b < gemm_grid){
    gemm_body<true>(b, x, Wp, a_src, a_dst, Hbf, as_, ad_, n);
  } else {
    int e = (b - gemm_grid) * 256 + threadIdx.x;
    if (e >= EP) return;
    int s, d;
    if (e < E){ s = src[e]; d = dst[e]; } else { s = d = e - E; }
    int pos = atomicAdd(&cursor[d], 1);
    csr[pos] = (ushort_t)s;
  }
}

// ---------------- aggregation: one wave per dst node, paired uint2 gather (R4 form) ----------------
template<bool OUTBF>
__global__ __launch_bounds__(256) void k_agg(const uint2* __restrict__ hb2,
                                             const ushort_t* __restrict__ csr,
                                             const int* __restrict__ rowptr,
                                             const float* __restrict__ asrc,
                                             const float* __restrict__ adst,
                                             const float* __restrict__ bias,
                                             ushort_t* __restrict__ outb,
                                             float* __restrict__ outf,
                                             int relu, int n){
  int node = (blockIdx.x * 256 + threadIdx.x) >> 6;
  if (node >= n) return;
  int lane = threadIdx.x & 63;
  int ll = lane & 31, half = lane >> 5;
  int beg = rowptr[node];
  int deg = rowptr[node + 1] - beg;
  float adn = adst[node];
  float4 acc = make_float4(0.f, 0.f, 0.f, 0.f);
  float inv;

  if (deg <= 64){
    int s = 0; float logit = -1e30f;
    if (lane < deg){
      s = csr[beg + lane];
      float xx = asrc[s] + adn;
      logit = xx >= 0.f ? xx : 0.2f * xx;
    }
    float m = wred_max(logit);
    float p = (lane < deg) ? __expf(logit - m) : 0.f;
    float denom = wred_sum(p);
    inv = 1.f / (denom + 1e-16f);
    int j = 0;
    for (; j + 4 <= deg; j += 4){
      int sA = __shfl(s, j, 64),     sB = __shfl(s, j + 1, 64);
      int sC = __shfl(s, j + 2, 64), sD = __shfl(s, j + 3, 64);
      float aA = __shfl(p, j, 64),     aB = __shfl(p, j + 1, 64);
      float aC = __shfl(p, j + 2, 64), aD = __shfl(p, j + 3, 64);
      int   r0 = half ? sB : sA;  float w0 = half ? aB : aA;
      int   r1 = half ? sD : sC;  float w1 = half ? aD : aC;
      uint2 v0 = hb2[(size_t)r0 * 32 + ll];
      uint2 v1 = hb2[(size_t)r1 * 32 + ll];
      acc.x += w0 * bflo(v0.x); acc.y += w0 * bfhi(v0.x);
      acc.z += w0 * bflo(v0.y); acc.w += w0 * bfhi(v0.y);
      acc.x += w1 * bflo(v1.x); acc.y += w1 * bfhi(v1.x);
      acc.z += w1 * bflo(v1.y); acc.w += w1 * bfhi(v1.y);
    }
    for (; j < deg; j += 2){
      int sA = __shfl(s, j, 64);
      int sB = (j + 1 < deg) ? __shfl(s, j + 1, 64) : sA;
      float aA = __shfl(p, j, 64);
      float aB = (j + 1 < deg) ? __shfl(p, j + 1, 64) : 0.f;
      int r0 = half ? sB : sA;  float w0 = half ? aB : aA;
      uint2 v0 = hb2[(size_t)r0 * 32 + ll];
      acc.x += w0 * bflo(v0.x); acc.y += w0 * bfhi(v0.x);
      acc.z += w0 * bflo(v0.y); acc.w += w0 * bfhi(v0.y);
    }
  } else {
    float m = -1e30f;
    for (int base = 0; base < deg; base += 64){
      float l = -1e30f;
      int idx = base + lane;
      if (idx < deg){ int sx = csr[beg + idx]; float xx = asrc[sx] + adn; l = xx >= 0.f ? xx : 0.2f * xx; }
      m = fmaxf(m, wred_max(l));
    }
    float denom = 0.f;
    for (int base = 0; base < deg; base += 64){
      float p2 = 0.f;
      int idx = base + lane;
      if (idx < deg){ int sx = csr[beg + idx]; float xx = asrc[sx] + adn; float l = xx >= 0.f ? xx : 0.2f * xx; p2 = __expf(l - m); }
      denom += wred_sum(p2);
    }
    inv = 1.f / (denom + 1e-16f);
    for (int base = 0; base < deg; base += 64){
      int cnt = deg - base; if (cnt > 64) cnt = 64;
      float p2 = 0.f; int sx = 0;
      int idx = base + lane;
      if (idx < deg){ sx = csr[beg + idx]; float xx = asrc[sx] + adn; float l = xx >= 0.f ? xx : 0.2f * xx; p2 = __expf(l - m); }
      for (int j = 0; j < cnt; j += 2){
        int sA = __shfl(sx, j, 64);
        int sB = (j + 1 < cnt) ? __shfl(sx, j + 1, 64) : sA;
        float aA = __shfl(p2, j, 64);
        float aB = (j + 1 < cnt) ? __shfl(p2, j + 1, 64) : 0.f;
        int r0 = half ? sB : sA;  float w0 = half ? aB : aA;
        uint2 v0 = hb2[(size_t)r0 * 32 + ll];
        acc.x += w0 * bflo(v0.x); acc.y += w0 * bfhi(v0.x);
        acc.z += w0 * bflo(v0.y); acc.w += w0 * bfhi(v0.y);
      }
    }
  }
  acc.x += __shfl_xor(acc.x, 32, 64);
  acc.y += __shfl_xor(acc.y, 32, 64);
  acc.z += __shfl_xor(acc.z, 32, 64);
  acc.w += __shfl_xor(acc.w, 32, 64);

  if (half == 0){
    float4 b4 = *(const float4*)&bias[ll * 4];
    float o0 = acc.x * inv + b4.x, o1 = acc.y * inv + b4.y;
    float o2 = acc.z * inv + b4.z, o3 = acc.w * inv + b4.w;
    if (relu){ o0 = fmaxf(o0, 0.f); o1 = fmaxf(o1, 0.f); o2 = fmaxf(o2, 0.f); o3 = fmaxf(o3, 0.f); }
    if (OUTBF){
      ushort4 u; u.x = f2bf(o0); u.y = f2bf(o1); u.z = f2bf(o2); u.w = f2bf(o3);
      *(ushort4*)&outb[(size_t)node * D + ll * 4] = u;
    } else {
      *(float4*)&outf[(size_t)node * D + ll * 4] = make_float4(o0, o1, o2, o3);
    }
  }
}

// ---------------- fused pool + final linear ----------------
__device__ __forceinline__ int lbound(const int* a, int n, int key){
  int lo = 0, hi = n;
  while (lo < hi){ int mid = (lo + hi) >> 1; if (a[mid] < key) lo = mid + 1; else hi = mid; }
  return lo;
}

__global__ __launch_bounds__(128) void k_pool_final(const float* __restrict__ x,
                                                    const int* __restrict__ batch,
                                                    const float* __restrict__ Wl,
                                                    const float* __restrict__ bl,
                                                    float* __restrict__ out, int n){
  __shared__ float pl[128];
  int g = blockIdx.x;
  int c = threadIdx.x;
  int lo = lbound(batch, n, g);
  int hi = lbound(batch, n, g + 1);
  float sum = 0.f;
  for (int i = lo; i < hi; i++) sum += x[(size_t)i * D + c];
  float cnt = (float)(hi - lo);
  pl[c] = sum / fmaxf(cnt, 1.f);
  __syncthreads();
  float acc = bl[c];
#pragma unroll 4
  for (int k = 0; k < 128; k++) acc += pl[k] * Wl[(size_t)k * D + c];
  out[(size_t)g * D + c] = acc;
}

// ---------------- launch ----------------
extern "C" void kernel_launch(void* const* d_in, const int* in_sizes, int n_in,
                              void* d_out, int out_size, void* d_ws, size_t ws_size,
                              hipStream_t stream){
  const float* x     = (const float*)d_in[0];
  const int*   ei    = (const int*)d_in[1];
  const int*   batch = (const int*)d_in[3];
  const float* gW[3]  = {(const float*)d_in[4],  (const float*)d_in[8],  (const float*)d_in[12]};
  const float* gAs[3] = {(const float*)d_in[5],  (const float*)d_in[9],  (const float*)d_in[13]};
  const float* gAd[3] = {(const float*)d_in[6],  (const float*)d_in[10], (const float*)d_in[14]};
  const float* gB[3]  = {(const float*)d_in[7],  (const float*)d_in[11], (const float*)d_in[15]};
  const float* linW = (const float*)d_in[16];
  const float* linB = (const float*)d_in[17];
  float* outp = (float*)d_out;

  int N  = in_sizes[3];
  int E  = in_sizes[1] / 2;
  int EP = E + N;
  int G  = out_size / D;

  char* ws = (char*)d_ws;
  size_t off = 0;
  auto alloc = [&](size_t bytes)->void*{
    void* p = ws + off;
    off += (bytes + 255) & ~(size_t)255;
    return p;
  };
  float*    bufF   = (float*)alloc((size_t)N * D * 4);      // layer-3 agg out (fp32)
  ushort_t* bufB   = (ushort_t*)alloc((size_t)N * D * 2);   // layer-1/2 agg out (bf16)
  ushort_t* Hbf    = (ushort_t*)alloc((size_t)N * D * 2);   // h (bf16)
  float*    as_    = (float*)alloc((size_t)N * 4);
  float*    ad_    = (float*)alloc((size_t)N * 4);
  int*      counts = (int*)  alloc((size_t)N * 4);
  int*      cursor = (int*)  alloc((size_t)N * 4);
  int*      rowptr = (int*)  alloc((size_t)(N + 1) * 4);
  ushort_t* csr    = (ushort_t*)alloc((size_t)EP * 2);
  int*      bsum   = (int*)  alloc(1024 * 4);
  ushort_t* Wp     = (ushort_t*)alloc(3 * 2 * 16384 * 2);   // 3 layers, hi+lo packed
  (void)ws_size; (void)n_in;

  const int* esrc = ei;
  const int* edst = ei + E;

  int tpb = 256;
  int egrid = (EP + tpb - 1) / tpb;
  int ngrid = (N + tpb - 1) / tpb;
  int gemm_grid = (N + 63) / 64;
  int node_grid = (N + 3) / 4;

  k_init <<<192 + ngrid, tpb, 0, stream>>>(gW[0], gW[1], gW[2], Wp, counts, N);
  k_hist <<<egrid, tpb, 0, stream>>>(edst, E, EP, counts);
  k_scan1<<<ngrid, tpb, 0, stream>>>(counts, N, rowptr, bsum);
  k_scan3<<<ngrid, tpb, 0, stream>>>(rowptr, bsum, cursor, N, EP);

  const uint2* hbu = (const uint2*)Hbf;

  // layer 1 GEMM (fp32 in) fused with CSR fill (independent, overlapped)
  k_gemm1_fill<<<gemm_grid + egrid, tpb, 0, stream>>>(x, Wp, gAs[0], gAd[0], Hbf, as_, ad_, N,
                                                      gemm_grid, esrc, edst, E, EP, cursor, csr);
  k_agg<true>  <<<node_grid, tpb, 0, stream>>>(hbu, csr, rowptr, as_, ad_, gB[0], bufB, nullptr, 1, N);
  // layer 2
  k_gemm_mfma_bf<<<gemm_grid, tpb, 0, stream>>>(bufB, Wp + 2 * 16384, gAs[1], gAd[1], Hbf, as_, ad_, N);
  k_agg<true>  <<<node_grid, tpb, 0, stream>>>(hbu, csr, rowptr, as_, ad_, gB[1], bufB, nullptr, 1, N);
  // layer 3
  k_gemm_mfma_bf<<<gemm_grid, tpb, 0, stream>>>(bufB, Wp + 4 * 16384, gAs[2], gAd[2], Hbf, as_, ad_, N);
  k_agg<false> <<<node_grid, tpb, 0, stream>>>(hbu, csr, rowptr, as_, ad_, gB[2], nullptr, bufF, 0, N);

  // fused pool + final linear
  k_pool_final<<<G, 128, 0, stream>>>(bufF, batch, linW, linB, outp, N);
}

// Round 8
// 216.120 us; speedup vs baseline: 1.4017x; 1.1371x over previous
//
#include <hip/hip_runtime.h>

#define D 128
typedef unsigned short ushort_t;
typedef __attribute__((ext_vector_type(8))) short bf16x8;
typedef __attribute__((ext_vector_type(4))) float f32x4;

// ---------------- helpers ----------------
__device__ __forceinline__ float wred_max(float v){
#pragma unroll
  for (int o = 1; o < 64; o <<= 1) v = fmaxf(v, __shfl_xor(v, o, 64));
  return v;
}
__device__ __forceinline__ float wred_sum(float v){
#pragma unroll
  for (int o = 1; o < 64; o <<= 1) v += __shfl_xor(v, o, 64);
  return v;
}
__device__ __forceinline__ unsigned short f2bf(float f){
  unsigned u = __float_as_uint(f);
  unsigned r = (u + 0x7FFFu + ((u >> 16) & 1u)) >> 16;   // RNE
  return (unsigned short)r;
}
__device__ __forceinline__ float bflo(unsigned u){ return __uint_as_float(u << 16); }
__device__ __forceinline__ float bfhi(unsigned u){ return __uint_as_float(u & 0xFFFF0000u); }

// ---------------- init: pack 3 W's hi-bf16 (blocks 0..191) + zero cnt (rest) ----------------
// B frag for 16x16x32: lane l holds B[k][c], c = ct*16+(l&15), k = s*32+(l>>4)*8+e.
__global__ __launch_bounds__(256) void k_init(const float* __restrict__ W0,
                                              const float* __restrict__ W1,
                                              const float* __restrict__ W2,
                                              ushort_t* __restrict__ Wp,
                                              int* __restrict__ cnt, int n){
  int b = blockIdx.x;
  if (b < 192){
    int wi = b >> 6;
    const float* W = wi == 0 ? W0 : (wi == 1 ? W1 : W2);
    ushort_t* dst = Wp + wi * 16384;
    int idx = (b & 63) * 256 + threadIdx.x;     // 0..16383
    int k = idx >> 7, c = idx & 127;
    int ct = c >> 4, s = k >> 5, lane = (c & 15) | (((k >> 3) & 3) << 4), e = k & 7;
    dst[((ct * 4 + s) * 64 + lane) * 8 + e] = f2bf(W[idx]);
  } else {
    int i = (b - 192) * 256 + threadIdx.x;
    if (i < n) cnt[i] = 0;
  }
}

// ---------------- MFMA GEMM body (hi-only, 32 mfma/wave) ----------------
template<bool XF32>
__device__ __forceinline__ void gemm_body(int bid, const void* __restrict__ Av,
                                          const ushort_t* __restrict__ Wp,
                                          const float* __restrict__ a_src,
                                          const float* __restrict__ a_dst,
                                          ushort_t* __restrict__ Hbf,
                                          float* __restrict__ as_,
                                          float* __restrict__ ad_,
                                          int n){
  int tid = threadIdx.x;
  int wid = tid >> 6, l = tid & 63;
  int kg = l >> 4, cin = l & 15;
  int r0 = bid * 64 + wid * 16;
  int row_l = r0 + cin;
  if (row_l > n - 1) row_l = n - 1;

  bf16x8 ah[4];
  if (XF32){
    const float* xp = (const float*)Av + (size_t)row_l * D + kg * 8;
#pragma unroll
    for (int s = 0; s < 4; s++){
      float4 f0 = *(const float4*)(xp + s * 32);
      float4 f1 = *(const float4*)(xp + s * 32 + 4);
      ah[s][0] = (short)f2bf(f0.x); ah[s][1] = (short)f2bf(f0.y);
      ah[s][2] = (short)f2bf(f0.z); ah[s][3] = (short)f2bf(f0.w);
      ah[s][4] = (short)f2bf(f1.x); ah[s][5] = (short)f2bf(f1.y);
      ah[s][6] = (short)f2bf(f1.z); ah[s][7] = (short)f2bf(f1.w);
    }
  } else {
    const ushort_t* xp = (const ushort_t*)Av + (size_t)row_l * D + kg * 8;
#pragma unroll
    for (int s = 0; s < 4; s++) ah[s] = *(const bf16x8*)(xp + s * 32);
  }

  const bf16x8* Bh = (const bf16x8*)Wp;

  f32x4 acc[8];
#pragma unroll
  for (int ct = 0; ct < 8; ct++) acc[ct] = (f32x4){0.f, 0.f, 0.f, 0.f};

#pragma unroll
  for (int ct = 0; ct < 8; ct++)
#pragma unroll
    for (int s = 0; s < 4; s++)
      acc[ct] = __builtin_amdgcn_mfma_f32_16x16x32_bf16(ah[s], Bh[(ct * 4 + s) * 64 + l], acc[ct], 0, 0, 0);

  float asv[8], adv[8];
#pragma unroll
  for (int ct = 0; ct < 8; ct++){
    asv[ct] = a_src[ct * 16 + cin];
    adv[ct] = a_dst[ct * 16 + cin];
  }
#pragma unroll
  for (int j = 0; j < 4; j++){
    float ps = 0.f, pd = 0.f;
#pragma unroll
    for (int ct = 0; ct < 8; ct++){ ps += acc[ct][j] * asv[ct]; pd += acc[ct][j] * adv[ct]; }
#pragma unroll
    for (int o = 1; o < 16; o <<= 1){ ps += __shfl_xor(ps, o, 64); pd += __shfl_xor(pd, o, 64); }
    int row = r0 + kg * 4 + j;
    if (row < n){
      if (cin == 0) as_[row] = ps;
      if (cin == 1) ad_[row] = pd;
#pragma unroll
      for (int ct = 0; ct < 8; ct++)
        Hbf[(size_t)row * D + ct * 16 + cin] = f2bf(acc[ct][j]);
    }
  }
}

// layer-2/3 GEMM
__global__ __launch_bounds__(256) void k_gemm_mfma_bf(const void* __restrict__ Av,
                                                      const ushort_t* __restrict__ Wp,
                                                      const float* __restrict__ a_src,
                                                      const float* __restrict__ a_dst,
                                                      ushort_t* __restrict__ Hbf,
                                                      float* __restrict__ as_,
                                                      float* __restrict__ ad_,
                                                      int n){
  gemm_body<false>(blockIdx.x, Av, Wp, a_src, a_dst, Hbf, as_, ad_, n);
}

// fused: blocks [0, gemm_grid) = layer-1 GEMM (fp32 in); rest = padded-CSR fill (overlapped)
__global__ __launch_bounds__(256) void k_gemm1_fill(const float* __restrict__ x,
                                                    const ushort_t* __restrict__ Wp,
                                                    const float* __restrict__ a_src,
                                                    const float* __restrict__ a_dst,
                                                    ushort_t* __restrict__ Hbf,
                                                    float* __restrict__ as_,
                                                    float* __restrict__ ad_,
                                                    int n, int gemm_grid,
                                                    const int* __restrict__ src,
                                                    const int* __restrict__ dst,
                                                    int E, int EP,
                                                    int* __restrict__ cnt,
                                                    ushort_t* __restrict__ csr_pad){
  int b = blockIdx.x;
  if (b < gemm_grid){
    gemm_body<true>(b, x, Wp, a_src, a_dst, Hbf, as_, ad_, n);
  } else {
    int e = (b - gemm_grid) * 256 + threadIdx.x;
    if (e >= EP) return;
    int s, d;
    if (e < E){ s = src[e]; d = dst[e]; } else { s = d = e - E; }
    int slot = atomicAdd(&cnt[d], 1);
    if (slot < 64) csr_pad[((size_t)d << 6) + slot] = (ushort_t)s;
  }
}

// ---------------- aggregation: one wave per node, quad uint4 gather ----------------
// lane = g*16 + q: group g (0..3) handles edge slot j+g, q indexes 16B of the row.
template<bool OUTBF>
__global__ __launch_bounds__(256) void k_agg(const uint4* __restrict__ hb4,   // 16 uint4 per row
                                             const ushort_t* __restrict__ csr_pad,
                                             const int* __restrict__ cnt,
                                             const float* __restrict__ asrc,
                                             const float* __restrict__ adst,
                                             const float* __restrict__ bias,
                                             ushort_t* __restrict__ outb,
                                             float* __restrict__ outf,
                                             int relu, int n){
  int node = (blockIdx.x * 256 + threadIdx.x) >> 6;
  if (node >= n) return;
  int lane = threadIdx.x & 63;
  int q = lane & 15, g = lane >> 4;
  int deg = cnt[node]; if (deg > 64) deg = 64;
  const ushort_t* eb = csr_pad + ((size_t)node << 6);
  float adn = adst[node];

  // softmax (lane-per-edge)
  int s = 0; float logit = -1e30f;
  if (lane < deg){
    s = eb[lane];
    float xx = asrc[s] + adn;
    logit = xx >= 0.f ? xx : 0.2f * xx;
  }
  float m = wred_max(logit);
  float p = (lane < deg) ? __expf(logit - m) : 0.f;
  float denom = wred_sum(p);
  float inv = 1.f / (denom + 1e-16f);

  // gather: 4 edges per iteration (one per group), full row per edge
  float acc[8] = {0.f, 0.f, 0.f, 0.f, 0.f, 0.f, 0.f, 0.f};
#pragma unroll 2
  for (int j = 0; j < deg; j += 4){
    int slot = j + g;                                  // <= 63 always (j <= 60)
    int   sj = __shfl(s, slot, 64);                    // lanes >= deg hold s=0 -> row 0, weight 0
    float wj = (slot < deg) ? __shfl(p, slot, 64) : 0.f;
    uint4 v = hb4[(size_t)sj * 16 + q];
    acc[0] += wj * bflo(v.x); acc[1] += wj * bfhi(v.x);
    acc[2] += wj * bflo(v.y); acc[3] += wj * bfhi(v.y);
    acc[4] += wj * bflo(v.z); acc[5] += wj * bfhi(v.z);
    acc[6] += wj * bflo(v.w); acc[7] += wj * bfhi(v.w);
  }

  // combine the 4 groups (lanes differing by 16, 32)
#pragma unroll
  for (int o = 16; o < 64; o <<= 1){
#pragma unroll
    for (int i = 0; i < 8; i++) acc[i] += __shfl_xor(acc[i], o, 64);
  }

  if (g == 0){
    float4 b0 = *(const float4*)&bias[q * 8];
    float4 b1 = *(const float4*)&bias[q * 8 + 4];
    float o0 = acc[0] * inv + b0.x, o1 = acc[1] * inv + b0.y;
    float o2 = acc[2] * inv + b0.z, o3 = acc[3] * inv + b0.w;
    float o4 = acc[4] * inv + b1.x, o5 = acc[5] * inv + b1.y;
    float o6 = acc[6] * inv + b1.z, o7 = acc[7] * inv + b1.w;
    if (relu){
      o0 = fmaxf(o0, 0.f); o1 = fmaxf(o1, 0.f); o2 = fmaxf(o2, 0.f); o3 = fmaxf(o3, 0.f);
      o4 = fmaxf(o4, 0.f); o5 = fmaxf(o5, 0.f); o6 = fmaxf(o6, 0.f); o7 = fmaxf(o7, 0.f);
    }
    if (OUTBF){
      ushort4 u0, u1;
      u0.x = f2bf(o0); u0.y = f2bf(o1); u0.z = f2bf(o2); u0.w = f2bf(o3);
      u1.x = f2bf(o4); u1.y = f2bf(o5); u1.z = f2bf(o6); u1.w = f2bf(o7);
      *(ushort4*)&outb[(size_t)node * D + q * 8]     = u0;
      *(ushort4*)&outb[(size_t)node * D + q * 8 + 4] = u1;
    } else {
      *(float4*)&outf[(size_t)node * D + q * 8]     = make_float4(o0, o1, o2, o3);
      *(float4*)&outf[(size_t)node * D + q * 8 + 4] = make_float4(o4, o5, o6, o7);
    }
  }
}

// ---------------- fused pool + final linear ----------------
__device__ __forceinline__ int lbound(const int* a, int n, int key){
  int lo = 0, hi = n;
  while (lo < hi){ int mid = (lo + hi) >> 1; if (a[mid] < key) lo = mid + 1; else hi = mid; }
  return lo;
}

__global__ __launch_bounds__(128) void k_pool_final(const float* __restrict__ x,
                                                    const int* __restrict__ batch,
                                                    const float* __restrict__ Wl,
                                                    const float* __restrict__ bl,
                                                    float* __restrict__ out, int n){
  __shared__ float pl[128];
  int g = blockIdx.x;
  int c = threadIdx.x;
  int lo = lbound(batch, n, g);
  int hi = lbound(batch, n, g + 1);
  float sum = 0.f;
  for (int i = lo; i < hi; i++) sum += x[(size_t)i * D + c];
  float cnt = (float)(hi - lo);
  pl[c] = sum / fmaxf(cnt, 1.f);
  __syncthreads();
  float acc = bl[c];
#pragma unroll 4
  for (int k = 0; k < 128; k++) acc += pl[k] * Wl[(size_t)k * D + c];
  out[(size_t)g * D + c] = acc;
}

// ---------------- launch ----------------
extern "C" void kernel_launch(void* const* d_in, const int* in_sizes, int n_in,
                              void* d_out, int out_size, void* d_ws, size_t ws_size,
                              hipStream_t stream){
  const float* x     = (const float*)d_in[0];
  const int*   ei    = (const int*)d_in[1];
  const int*   batch = (const int*)d_in[3];
  const float* gW[3]  = {(const float*)d_in[4],  (const float*)d_in[8],  (const float*)d_in[12]};
  const float* gAs[3] = {(const float*)d_in[5],  (const float*)d_in[9],  (const float*)d_in[13]};
  const float* gAd[3] = {(const float*)d_in[6],  (const float*)d_in[10], (const float*)d_in[14]};
  const float* gB[3]  = {(const float*)d_in[7],  (const float*)d_in[11], (const float*)d_in[15]};
  const float* linW = (const float*)d_in[16];
  const float* linB = (const float*)d_in[17];
  float* outp = (float*)d_out;

  int N  = in_sizes[3];
  int E  = in_sizes[1] / 2;
  int EP = E + N;
  int G  = out_size / D;

  char* ws = (char*)d_ws;
  size_t off = 0;
  auto alloc = [&](size_t bytes)->void*{
    void* p = ws + off;
    off += (bytes + 255) & ~(size_t)255;
    return p;
  };
  float*    bufF    = (float*)alloc((size_t)N * D * 4);      // layer-3 agg out (fp32)
  ushort_t* bufB    = (ushort_t*)alloc((size_t)N * D * 2);   // layer-1/2 agg out (bf16)
  ushort_t* Hbf     = (ushort_t*)alloc((size_t)N * D * 2);   // h (bf16)
  float*    as_     = (float*)alloc((size_t)N * 4);
  float*    ad_     = (float*)alloc((size_t)N * 4);
  int*      cnt     = (int*)  alloc((size_t)N * 4);
  ushort_t* csr_pad = (ushort_t*)alloc((size_t)N * 64 * 2);  // padded CSR, K=64
  ushort_t* Wp      = (ushort_t*)alloc(3 * 16384 * 2);       // 3 packed W (hi only)
  (void)ws_size; (void)n_in;

  const int* esrc = ei;
  const int* edst = ei + E;

  int tpb = 256;
  int egrid = (EP + tpb - 1) / tpb;
  int ngrid = (N + tpb - 1) / tpb;
  int gemm_grid = (N + 63) / 64;
  int node_grid = (N + 3) / 4;

  k_init<<<192 + ngrid, tpb, 0, stream>>>(gW[0], gW[1], gW[2], Wp, cnt, N);

  const uint4* hbu = (const uint4*)Hbf;

  // layer 1 GEMM (fp32 in) fused with padded-CSR fill (independent, overlapped)
  k_gemm1_fill<<<gemm_grid + egrid, tpb, 0, stream>>>(x, Wp, gAs[0], gAd[0], Hbf, as_, ad_, N,
                                                      gemm_grid, esrc, edst, E, EP, cnt, csr_pad);
  k_agg<true>  <<<node_grid, tpb, 0, stream>>>(hbu, csr_pad, cnt, as_, ad_, gB[0], bufB, nullptr, 1, N);
  // layer 2
  k_gemm_mfma_bf<<<gemm_grid, tpb, 0, stream>>>(bufB, Wp + 16384, gAs[1], gAd[1], Hbf, as_, ad_, N);
  k_agg<true>  <<<node_grid, tpb, 0, stream>>>(hbu, csr_pad, cnt, as_, ad_, gB[1], bufB, nullptr, 1, N);
  // layer 3
  k_gemm_mfma_bf<<<gemm_grid, tpb, 0, stream>>>(bufB, Wp + 32768, gAs[2], gAd[2], Hbf, as_, ad_, N);
  k_agg<false> <<<node_grid, tpb, 0, stream>>>(hbu, csr_pad, cnt, as_, ad_, gB[2], nullptr, bufF, 0, N);

  // fused pool + final linear
  k_pool_final<<<G, 128, 0, stream>>>(bufF, batch, linW, linB, outp, N);
}